// Round 6
// baseline (408.546 us; speedup 1.0000x reference)
//
#include <hip/hip_runtime.h>

// InfoNCE loss:
//   loss = (1/B) * sum_i [ log(sum_j exp(Q_i . D_j / T)) - Q_i . D_{i*dp} / T ]
//
// R10 = the 4-phase 256x256 MX-fp8 schedule, re-divided over 16 WAVES
// (1024 threads) so per-wave register demand FITS the 128-VGPR budget the
// compiler insists on (R8/R9 post-mortem: 8-wave version needs ~210 regs,
// got 128, spilled acc -> ~1GB scratch traffic/dispatch, MfmaUtil 5%).
//   - per-wave C = 64x64 = 16 frags = 64 acc VGPRs; per phase 4A+2B frag
//     temps (48) -> peak ~122 < 128. No spill by construction.
//   - 16 waves = 4 waves/SIMD at 1 block/CU: 2x the TLP of the 8-wave
//     version for latency hiding; setprio has real arbitration room.
//   - 2 phases per K-tile (BK=128), phase = N-half: 12 ds_read_b128 ||
//     2 global_load_lds (next tile) ; s_barrier ; lgkmcnt(0) ; setprio(1) ;
//     8 MFMA ; setprio(0) ; [phase1: vmcnt(0), aged >= 1 MFMA cluster] ;
//     s_barrier.  Single vmcnt(0) per K-tile, never mid-pipeline.
//   - XCD swizzle kept (verified R7: FETCH halved).
//   - All register-file indices literal via phase macro (rule #20).
//
// Tiled global layout (per matrix, unchanged): for 128-row block R, 128-wide
// k-block k0b: 16KB image = 16 chunks x 1KB. Chunk c = rg*2 + kh (rg=0..7
// 16-row group, kh=0..1 64-col half); slot l (16B) holds
//   X[R*128 + rg*16 + (l&15)][k0b*128 + kh*64 + (l>>4)*16 .. +16]   (fp8)
//
// ws layout (~12.1 MB):
//   [0)       Q8  B*K fp8     (4 MB)
//   [B*K)     D8  N*K fp8     (8 MB)
//   [+N*K)    rowsum B f32    (16 KB)  zeroed by cvt kernel
//   [+B*4)    pos    B f32    (16 KB)  written by gemm epilogue

#define TEMP_INV 50.0f
#define PRESCALE 16.0f
#define SCALE_BYTE 123   // e8m0: 2^(123-127) = 2^-4 per operand

typedef int   i32x4 __attribute__((ext_vector_type(4)));
typedef int   i32x8 __attribute__((ext_vector_type(8)));
typedef float f32x4 __attribute__((ext_vector_type(4)));

// ---------------- fp32 -> fp8 e4m3 (x16), pre-tiled; zero rowsum ----------
__global__ void cvt_kernel(const float* __restrict__ Q, const float* __restrict__ Dm,
                           unsigned int* __restrict__ Q8, unsigned int* __restrict__ D8,
                           float* __restrict__ rowsum, int qSlots, int B, int K) {
    const int gid = blockIdx.x * blockDim.x + threadIdx.x;
    if (gid < B) rowsum[gid] = 0.0f;
    const float* src;
    unsigned int* dst;
    int s;
    if (gid < qSlots) { src = Q;  dst = Q8; s = gid; }
    else              { src = Dm; dst = D8; s = gid - qSlots; }
    // Slot permutation within the 64-slot chunk (R7, kept): lane l handles
    // slot ((l&3)<<4)|(l>>2) -> reads coalesce to 256B runs.
    {
        const int l0 = s & 63;
        s = (s & ~63) | (((l0 & 3) << 4) | (l0 >> 2));
    }
    const int l   = s & 63;
    const int c   = (s >> 6) & 15;
    const int k0b = (s >> 10) & 7;
    const int R   = s >> 13;
    const int row = R * 128 + (c >> 1) * 16 + (l & 15);
    const int k   = k0b * 128 + (c & 1) * 64 + (l >> 4) * 16;
    const float* p = src + (size_t)row * K + k;
    unsigned int w[4];
#pragma unroll
    for (int d = 0; d < 4; ++d) {
        float4 v = *(const float4*)(p + d * 4);
        int t = __builtin_amdgcn_cvt_pk_fp8_f32(v.x * PRESCALE, v.y * PRESCALE, 0, false);
        t = __builtin_amdgcn_cvt_pk_fp8_f32(v.z * PRESCALE, v.w * PRESCALE, t, true);
        w[d] = (unsigned int)t;
    }
    *(uint4*)(dst + (size_t)s * 4) = make_uint4(w[0], w[1], w[2], w[3]);
}

// ---------------- fused MX-fp8 GEMM + row sum-exp + pos extraction --------
// grid: 1D 512 blocks (XCD-swizzled), 1024 threads = 16 waves (4M x 4N),
// per-wave C = 64x64. BK=128, 2 phases/K-tile, 128KB LDS ring.
__global__ __launch_bounds__(1024) void gemm_expsum_kernel(
        const unsigned int* __restrict__ Q8, const unsigned int* __restrict__ D8,
        const int* __restrict__ dper,
        float* __restrict__ rowsum, float* __restrict__ pos, int K) {
    __shared__ unsigned int BUF[32768];   // 128KB: 2 x (A 8192 dw + B 8192 dw)

    const int tid   = threadIdx.x;
    const int wave  = tid >> 6;
    const int lane  = tid & 63;
    const int wr    = wave >> 2;         // 0..3 -> 64-row strip
    const int wc    = wave & 3;          // 0..3 -> 64-col strip
    const int lquad = lane >> 4;
    const int lm    = lane & 15;
    const int lh2   = lquad >> 1;        // kh (64-col half) for frag reads

    // XCD-aware bijective swizzle: 512 = 8 XCDs x (8bx x 8by) sub-tiles.
    const int f   = blockIdx.x;
    const int xcd = f & 7;
    const int sub = f >> 3;              // 0..63
    const int bx  = (xcd & 1) * 8 + (sub & 7);    // 0..15
    const int by  = (xcd >> 1) * 8 + (sub >> 3);  // 0..31

    const int KB = K >> 7;               // 8 K-tiles of 128

    // ---- staging: wave w owns 4 chunks fl = (w&7)*4 + q of its matrix ----
    // waves 0-7 stage A (chunks 0..31), waves 8-15 stage B.
    // fl = rb*16 + c  (rb = image within the 2-image 256-row set, c = chunk).
    const bool isB = wave >= 8;
    const unsigned int* sbase = isB ? D8 : Q8;
    const int bb  = isB ? by : bx;
    const int w7  = wave & 7;
    const int rb  = w7 >> 2;             // constant per wave (q<4 never crosses)
    // dword index from sbase for chunk q at k-tile kb:
    //   (2*bb+rb)*KB*4096 + kb*4096 + ((w7&3)*4+q)*256 + lane*4
    const unsigned int sidx0 = (unsigned int)((2 * bb + rb) * (KB * 4096)
                                              + (w7 & 3) * 4 * 256 + lane * 4);
    const unsigned int dofs0 = (unsigned int)((isB ? 8192 : 0) + w7 * 4 * 256 + lane * 4);

    // ---- fragment LDS dword offsets (within ring slot) ----
    // A frag i (rows wr*64+16i): image wr>>1, rg=(wr&1)*4+i, chunk rg*2+kh.
    const int slotofs = ((lquad & 1) * 32 + lm) * 4;
    const int aobase = ((wr >> 1) * 16 + (wr & 1) * 8 + lh2) * 256 + slotofs;        // +i*512
    const int bobase = 8192 + ((wc >> 1) * 16 + (wc & 1) * 8 + lh2) * 256 + slotofs; // +j_abs*512

    f32x4 acc[16];
#pragma unroll
    for (int t = 0; t < 16; ++t) acc[t] = (f32x4){0.f, 0.f, 0.f, 0.f};

    // ---- prologue: stage tile 0 into slot 0, drain, publish ----
#pragma unroll
    for (int q = 0; q < 4; ++q)
        __builtin_amdgcn_global_load_lds(
            (const __attribute__((address_space(1))) void*)(sbase + sidx0 + q * 256),
            (__attribute__((address_space(3))) void*)(BUF + dofs0 + q * 256), 16, 0, 0);
    asm volatile("s_waitcnt vmcnt(0)" ::: "memory");
    __builtin_amdgcn_s_barrier();

#define LDFRAG(dst_, base_, off_) do {                                       \
        i32x4 lo_ = *(const i32x4*)((base_) + (off_));                       \
        i32x4 hi_ = *(const i32x4*)((base_) + (off_) + 64);                  \
        dst_ = __builtin_shufflevector(lo_, hi_, 0, 1, 2, 3, 4, 5, 6, 7);    \
    } while (0)

#define MFMA1(AA, BB, IDX)                                                   \
        acc[IDX] = __builtin_amdgcn_mfma_scale_f32_16x16x128_f8f6f4(         \
            AA, BB, acc[IDX], 0, 0, 0, SCALE_BYTE, 0, SCALE_BYTE)

    // One phase, LITERAL N-half index NH (0/1). All reg-file indices are
    // integer constant expressions.
#define PHASE(NH, pf_) do {                                                  \
        i32x8 A0, A1, A2, A3, B0, B1;                                        \
        LDFRAG(A0, bp, aobase + 0 * 512);                                    \
        LDFRAG(A1, bp, aobase + 1 * 512);                                    \
        LDFRAG(A2, bp, aobase + 2 * 512);                                    \
        LDFRAG(A3, bp, aobase + 3 * 512);                                    \
        LDFRAG(B0, bp, bobase + ((NH) * 2 + 0) * 512);                       \
        LDFRAG(B1, bp, bobase + ((NH) * 2 + 1) * 512);                       \
        if (pf_) {                                                           \
            __builtin_amdgcn_global_load_lds(                                \
                (const __attribute__((address_space(1))) void*)(sbase + sidx0 + ((NH) * 2 + 0) * 256 + soff), \
                (__attribute__((address_space(3))) void*)(np + dofs0 + ((NH) * 2 + 0) * 256), 16, 0, 0); \
            __builtin_amdgcn_global_load_lds(                                \
                (const __attribute__((address_space(1))) void*)(sbase + sidx0 + ((NH) * 2 + 1) * 256 + soff), \
                (__attribute__((address_space(3))) void*)(np + dofs0 + ((NH) * 2 + 1) * 256), 16, 0, 0); \
        }                                                                    \
        __builtin_amdgcn_s_barrier();                                        \
        asm volatile("s_waitcnt lgkmcnt(0)" ::: "memory");                   \
        __builtin_amdgcn_s_setprio(1);                                       \
        MFMA1(A0, B0, 0 * 4 + (NH) * 2 + 0);                                 \
        MFMA1(A0, B1, 0 * 4 + (NH) * 2 + 1);                                 \
        MFMA1(A1, B0, 1 * 4 + (NH) * 2 + 0);                                 \
        MFMA1(A1, B1, 1 * 4 + (NH) * 2 + 1);                                 \
        MFMA1(A2, B0, 2 * 4 + (NH) * 2 + 0);                                 \
        MFMA1(A2, B1, 2 * 4 + (NH) * 2 + 1);                                 \
        MFMA1(A3, B0, 3 * 4 + (NH) * 2 + 0);                                 \
        MFMA1(A3, B1, 3 * 4 + (NH) * 2 + 1);                                 \
        __builtin_amdgcn_s_setprio(0);                                       \
        if ((NH) == 1 && (pf_))                                              \
            asm volatile("s_waitcnt vmcnt(0)" ::: "memory");                 \
        __builtin_amdgcn_s_barrier();                                        \
    } while (0)

    int cur = 0;
    for (int kb = 0; kb < KB; ++kb, cur ^= 1) {
        const bool pf = (kb + 1 < KB);
        const unsigned int* bp = BUF + cur * 16384;
        unsigned int* np = BUF + (cur ^ 1) * 16384;
        const unsigned int soff = (unsigned int)((kb + 1) * 4096);
        PHASE(0, pf);
        PHASE(1, pf);
    }
#undef PHASE
#undef MFMA1
#undef LDFRAG

    // ---- epilogue. 16x16 C layout: col = lane&15, row = (lane>>4)*4+reg ----
    const int dp  = dper[0];
    const int gr0 = bx * 256 + wr * 64 + 4 * lquad;
    const int gc0 = by * 256 + wc * 64 + lm;
#pragma unroll
    for (int i = 0; i < 4; ++i)
#pragma unroll
        for (int r = 0; r < 4; ++r) {
            const int gr = gr0 + 16 * i + r;
            float e = 0.0f;
#pragma unroll
            for (int j = 0; j < 4; ++j) {
                float v = acc[i * 4 + j][r] * TEMP_INV;
                if (gr * dp == gc0 + 16 * j) pos[gr] = v;
                e += __expf(v);
            }
            e += __shfl_xor(e, 1);
            e += __shfl_xor(e, 2);
            e += __shfl_xor(e, 4);
            e += __shfl_xor(e, 8);
            if (lm == 0) atomicAdd(&rowsum[gr], e);
        }
}

// ---------------- final: loss = sum(log(rowsum) - pos)/B ----------------
__global__ void final_kernel(const float* __restrict__ rowsum,
                             const float* __restrict__ pos,
                             float* __restrict__ out, int B) {
    __shared__ float red[16];
    int tid = threadIdx.x;   // 1024 threads
    float s = 0.0f;
    for (int i = tid; i < B; i += blockDim.x)
        s += __logf(rowsum[i]) - pos[i];
    s += __shfl_xor(s, 32);
    s += __shfl_xor(s, 16);
    s += __shfl_xor(s, 8);
    s += __shfl_xor(s, 4);
    s += __shfl_xor(s, 2);
    s += __shfl_xor(s, 1);
    int w = tid >> 6, l = tid & 63;
    if (l == 0) red[w] = s;
    __syncthreads();
    if (tid == 0) {
        float t = 0.0f;
        int nw = blockDim.x >> 6;
        for (int i = 0; i < nw; ++i) t += red[i];
        out[0] = t / (float)B;
    }
}

extern "C" void kernel_launch(void* const* d_in, const int* in_sizes, int n_in,
                              void* d_out, int out_size, void* d_ws, size_t ws_size,
                              hipStream_t stream) {
    const float* Q   = (const float*)d_in[0];
    const float* Dm  = (const float*)d_in[1];
    const int* dper  = (const int*)d_in[2];
    float* out = (float*)d_out;

    const int DIM  = 1024;
    const int B    = in_sizes[0] / DIM;   // 4096
    const int Ntot = in_sizes[1] / DIM;   // 8192

    unsigned int* Q8 = (unsigned int*)d_ws;
    unsigned int* D8 = Q8 + (size_t)B * DIM / 4;
    float* rowsum = (float*)(D8 + (size_t)Ntot * DIM / 4);
    float* pos = rowsum + B;

    const int qSlots = B * DIM / 16;            // 262144
    const int dSlots = Ntot * DIM / 16;         // 524288
    cvt_kernel<<<(qSlots + dSlots) / 256, 256, 0, stream>>>(
        Q, Dm, Q8, D8, rowsum, qSlots, B, DIM);

    const int nblk = (B / 256) * (Ntot / 256);  // 512 = 8 * 64
    gemm_expsum_kernel<<<nblk, 1024, 0, stream>>>(Q8, D8, dper, rowsum, pos, DIM);

    final_kernel<<<1, 1024, 0, stream>>>(rowsum, pos, out, B);
}

// Round 7
// 334.453 us; speedup vs baseline: 1.2215x; 1.2215x over previous
//
#include <hip/hip_runtime.h>

// InfoNCE loss:
//   loss = (1/B) * sum_i [ log(sum_j exp(Q_i . D_j / T)) - Q_i . D_{i*dp} / T ]
//
// R11 = R9 byte-identical EXCEPT __launch_bounds__(512, 1).
//
// Allocator law identified from R8/R9/R10 counters (VGPR_Count 128/128/64 at
// blockDim 512/512/1024): the toolchain budgets registers for 2 BLOCKS/CU by
// default, and the 2nd __launch_bounds__ arg acts as CUDA minBlocksPerCU.
// R8's "(512,2)" REQUESTED the 128-reg cap; R9/R10 inherited the default.
// The 256x256 4-phase schedule needs ~210 regs/thread -> it has never run
// unspilled (WRITE_SIZE 647-887MB of scratch, MfmaUtil ~5%).
// (512, 1) => budget 256 regs/wave (2 waves/SIMD), demand ~210 -> no spill.
// LDS=128KB already limits to 1 block/CU, so nothing is sacrificed.
//
// Schedule per K-tile (BK=128), unchanged:
//   phase p = C-quadrant (Mh,Nh):
//     12 ds_read_b128 (4 A + 2 B frags) from buf[cur]
//     2 global_load_lds chunks of tile kb+1 into buf[cur^1]
//     s_barrier ; lgkmcnt(0) ; setprio(1) ; 8 MFMA ; setprio(0)
//     [phase 3 only: vmcnt(0) -- prefetch aged >= 3 MFMA clusters]
//     s_barrier
// XCD swizzle (verified R7: FETCH halved): 512 blocks = 8 XCDs x (8x8).
//
// Tiled global layout (per matrix, unchanged): for 128-row block R, 128-wide
// k-block k0b: 16KB image = 16 chunks x 1KB. Chunk c = rg*2 + kh (rg=0..7
// 16-row group, kh=0..1 64-col half); slot l (16B) holds
//   X[R*128 + rg*16 + (l&15)][k0b*128 + kh*64 + (l>>4)*16 .. +16]   (fp8)
//
// ws layout (~12.1 MB):
//   [0)       Q8  B*K fp8     (4 MB)
//   [B*K)     D8  N*K fp8     (8 MB)
//   [+N*K)    rowsum B f32    (16 KB)  zeroed by cvt kernel
//   [+B*4)    pos    B f32    (16 KB)  written by gemm epilogue

#define TEMP_INV 50.0f
#define PRESCALE 16.0f
#define SCALE_BYTE 123   // e8m0: 2^(123-127) = 2^-4 per operand

typedef int   i32x4 __attribute__((ext_vector_type(4)));
typedef int   i32x8 __attribute__((ext_vector_type(8)));
typedef float f32x4 __attribute__((ext_vector_type(4)));

// ---------------- fp32 -> fp8 e4m3 (x16), pre-tiled; zero rowsum ----------
__global__ void cvt_kernel(const float* __restrict__ Q, const float* __restrict__ Dm,
                           unsigned int* __restrict__ Q8, unsigned int* __restrict__ D8,
                           float* __restrict__ rowsum, int qSlots, int B, int K) {
    const int gid = blockIdx.x * blockDim.x + threadIdx.x;
    if (gid < B) rowsum[gid] = 0.0f;
    const float* src;
    unsigned int* dst;
    int s;
    if (gid < qSlots) { src = Q;  dst = Q8; s = gid; }
    else              { src = Dm; dst = D8; s = gid - qSlots; }
    // Slot permutation within the 64-slot chunk (R7, kept): lane l handles
    // slot ((l&3)<<4)|(l>>2) -> reads coalesce to 256B runs.
    {
        const int l0 = s & 63;
        s = (s & ~63) | (((l0 & 3) << 4) | (l0 >> 2));
    }
    const int l   = s & 63;
    const int c   = (s >> 6) & 15;
    const int k0b = (s >> 10) & 7;
    const int R   = s >> 13;
    const int row = R * 128 + (c >> 1) * 16 + (l & 15);
    const int k   = k0b * 128 + (c & 1) * 64 + (l >> 4) * 16;
    const float* p = src + (size_t)row * K + k;
    unsigned int w[4];
#pragma unroll
    for (int d = 0; d < 4; ++d) {
        float4 v = *(const float4*)(p + d * 4);
        int t = __builtin_amdgcn_cvt_pk_fp8_f32(v.x * PRESCALE, v.y * PRESCALE, 0, false);
        t = __builtin_amdgcn_cvt_pk_fp8_f32(v.z * PRESCALE, v.w * PRESCALE, t, true);
        w[d] = (unsigned int)t;
    }
    *(uint4*)(dst + (size_t)s * 4) = make_uint4(w[0], w[1], w[2], w[3]);
}

// ---------------- fused MX-fp8 GEMM + row sum-exp + pos extraction --------
// grid: 1D 512 blocks (XCD-swizzled), 512 threads = 8 waves (2Mx4N),
// BK=128, 4-phase schedule, 128KB LDS ring. minBlocksPerCU=1 -> 256-reg budget.
__global__ __launch_bounds__(512, 1) void gemm_expsum_kernel(
        const unsigned int* __restrict__ Q8, const unsigned int* __restrict__ D8,
        const int* __restrict__ dper,
        float* __restrict__ rowsum, float* __restrict__ pos, int K) {
    __shared__ unsigned int BUF[32768];   // 128KB: 2 x (A 8192 dw + B 8192 dw)

    const int tid   = threadIdx.x;
    const int wave  = tid >> 6;
    const int lane  = tid & 63;
    const int wr    = wave >> 2;         // 0..1 -> 128-row half
    const int wc    = wave & 3;          // 0..3 -> 64-col strip
    const int lquad = lane >> 4;
    const int lm    = lane & 15;
    const int lh2   = lquad >> 1;        // kh for fragment reads

    // XCD-aware bijective swizzle: 512 = 8 XCDs x (8bx x 8by) sub-tiles.
    const int f   = blockIdx.x;
    const int xcd = f & 7;
    const int sub = f >> 3;              // 0..63
    const int bx  = (xcd & 1) * 8 + (sub & 7);    // 0..15
    const int by  = (xcd >> 1) * 8 + (sub >> 3);  // 0..31

    const int KB = K >> 7;               // 8 K-tiles of 128

    // ---- staging: wave w owns chunks flat = w*8 + 2p + q (p=phase) ----
    // waves 0-3 stage A (chunks 0..31), waves 4-7 stage B (chunks 32..63).
    const unsigned int* sbase = (wave < 4) ? Q8 : D8;
    const int bb = (wave < 4) ? bx : by;
    unsigned int sidx[8];                // dword index from sbase (+kb*4096)
    unsigned int dofs[8];                // dword offset within ring slot
#pragma unroll
    for (int q = 0; q < 8; ++q) {
        const int fl = (wave & 3) * 8 + q;        // 0..31 within A or B set
        const int rb = fl >> 4;                   // which 128-row image
        const int c  = fl & 15;                   // chunk within image
        sidx[q] = (unsigned int)((2 * bb + rb) * (KB * 4096) + c * 256 + lane * 4);
        dofs[q] = (unsigned int)((wave * 8 + q) * 256 + lane * 4);   // A:0..8191, B:8192..
    }

    // ---- fragment LDS dword offsets (within ring slot; bp adds cur) ----
    const int slotofs = ((lquad & 1) * 32 + lm) * 4;
    const int ao0 = (wr * 16 + lh2) * 256 + slotofs;          // A frag i_abs: +i_abs*512
    const int bo0 = 8192 + (wc * 8 + lh2) * 256 + slotofs;    // B frag j_abs: +j_abs*512

    f32x4 acc[32];
#pragma unroll
    for (int t = 0; t < 32; ++t) acc[t] = (f32x4){0.f, 0.f, 0.f, 0.f};

    // ---- prologue: stage tile 0 into slot 0, drain, publish ----
#pragma unroll
    for (int q = 0; q < 8; ++q)
        __builtin_amdgcn_global_load_lds(
            (const __attribute__((address_space(1))) void*)(sbase + sidx[q]),
            (__attribute__((address_space(3))) void*)(BUF + dofs[q]), 16, 0, 0);
    asm volatile("s_waitcnt vmcnt(0)" ::: "memory");
    __builtin_amdgcn_s_barrier();

    // One phase, LITERAL index PP (0..3). All register-file indices are
    // integer constant expressions -> nothing can fall to scratch.
#define LDFRAG(dst_, base_, off_) do {                                       \
        i32x4 lo_ = *(const i32x4*)((base_) + (off_));                       \
        i32x4 hi_ = *(const i32x4*)((base_) + (off_) + 64);                  \
        dst_ = __builtin_shufflevector(lo_, hi_, 0, 1, 2, 3, 4, 5, 6, 7);    \
    } while (0)

#define MFMA1(AA, BB, IDX)                                                   \
        acc[IDX] = __builtin_amdgcn_mfma_scale_f32_16x16x128_f8f6f4(         \
            AA, BB, acc[IDX], 0, 0, 0, SCALE_BYTE, 0, SCALE_BYTE)

#define PHASE(PP, pf_) do {                                                  \
        constexpr int Mh_ = (PP) >> 1, Nh_ = (PP) & 1;                       \
        i32x8 A0, A1, A2, A3, B0, B1;                                        \
        LDFRAG(A0, bp, ao0 + (Mh_ * 4 + 0) * 512);                           \
        LDFRAG(A1, bp, ao0 + (Mh_ * 4 + 1) * 512);                           \
        LDFRAG(A2, bp, ao0 + (Mh_ * 4 + 2) * 512);                           \
        LDFRAG(A3, bp, ao0 + (Mh_ * 4 + 3) * 512);                           \
        LDFRAG(B0, bp, bo0 + (Nh_ * 2 + 0) * 512);                           \
        LDFRAG(B1, bp, bo0 + (Nh_ * 2 + 1) * 512);                           \
        if (pf_) {                                                           \
            __builtin_amdgcn_global_load_lds(                                \
                (const __attribute__((address_space(1))) void*)(sbase + sidx[(PP) * 2] + soff), \
                (__attribute__((address_space(3))) void*)(np + dofs[(PP) * 2]), 16, 0, 0); \
            __builtin_amdgcn_global_load_lds(                                \
                (const __attribute__((address_space(1))) void*)(sbase + sidx[(PP) * 2 + 1] + soff), \
                (__attribute__((address_space(3))) void*)(np + dofs[(PP) * 2 + 1]), 16, 0, 0); \
        }                                                                    \
        __builtin_amdgcn_s_barrier();                                        \
        asm volatile("s_waitcnt lgkmcnt(0)" ::: "memory");                   \
        __builtin_amdgcn_s_setprio(1);                                       \
        MFMA1(A0, B0, (Mh_ * 4 + 0) * 4 + Nh_ * 2 + 0);                      \
        MFMA1(A0, B1, (Mh_ * 4 + 0) * 4 + Nh_ * 2 + 1);                      \
        MFMA1(A1, B0, (Mh_ * 4 + 1) * 4 + Nh_ * 2 + 0);                      \
        MFMA1(A1, B1, (Mh_ * 4 + 1) * 4 + Nh_ * 2 + 1);                      \
        MFMA1(A2, B0, (Mh_ * 4 + 2) * 4 + Nh_ * 2 + 0);                      \
        MFMA1(A2, B1, (Mh_ * 4 + 2) * 4 + Nh_ * 2 + 1);                      \
        MFMA1(A3, B0, (Mh_ * 4 + 3) * 4 + Nh_ * 2 + 0);                      \
        MFMA1(A3, B1, (Mh_ * 4 + 3) * 4 + Nh_ * 2 + 1);                      \
        __builtin_amdgcn_s_setprio(0);                                       \
        if ((PP) == 3 && (pf_))                                              \
            asm volatile("s_waitcnt vmcnt(0)" ::: "memory");                 \
        __builtin_amdgcn_s_barrier();                                        \
    } while (0)

    int cur = 0;
    for (int kb = 0; kb < KB; ++kb, cur ^= 1) {
        const bool pf = (kb + 1 < KB);
        const unsigned int* bp = BUF + cur * 16384;
        unsigned int* np = BUF + (cur ^ 1) * 16384;
        const unsigned int soff = (unsigned int)((kb + 1) * 4096);
        PHASE(0, pf);
        PHASE(1, pf);
        PHASE(2, pf);
        PHASE(3, pf);
    }
#undef PHASE
#undef MFMA1
#undef LDFRAG

    // ---- epilogue. 16x16 C layout: col = lane&15, row = (lane>>4)*4+reg ----
    const int dp  = dper[0];
    const int gr0 = bx * 256 + wr * 128 + 4 * lquad;
    const int gc0 = by * 256 + wc * 64 + lm;
#pragma unroll
    for (int i = 0; i < 8; ++i)
#pragma unroll
        for (int r = 0; r < 4; ++r) {
            const int gr = gr0 + 16 * i + r;
            float e = 0.0f;
#pragma unroll
            for (int j = 0; j < 4; ++j) {
                float v = acc[i * 4 + j][r] * TEMP_INV;
                if (gr * dp == gc0 + 16 * j) pos[gr] = v;
                e += __expf(v);
            }
            e += __shfl_xor(e, 1);
            e += __shfl_xor(e, 2);
            e += __shfl_xor(e, 4);
            e += __shfl_xor(e, 8);
            if (lm == 0) atomicAdd(&rowsum[gr], e);
        }
}

// ---------------- final: loss = sum(log(rowsum) - pos)/B ----------------
__global__ void final_kernel(const float* __restrict__ rowsum,
                             const float* __restrict__ pos,
                             float* __restrict__ out, int B) {
    __shared__ float red[16];
    int tid = threadIdx.x;   // 1024 threads
    float s = 0.0f;
    for (int i = tid; i < B; i += blockDim.x)
        s += __logf(rowsum[i]) - pos[i];
    s += __shfl_xor(s, 32);
    s += __shfl_xor(s, 16);
    s += __shfl_xor(s, 8);
    s += __shfl_xor(s, 4);
    s += __shfl_xor(s, 2);
    s += __shfl_xor(s, 1);
    int w = tid >> 6, l = tid & 63;
    if (l == 0) red[w] = s;
    __syncthreads();
    if (tid == 0) {
        float t = 0.0f;
        int nw = blockDim.x >> 6;
        for (int i = 0; i < nw; ++i) t += red[i];
        out[0] = t / (float)B;
    }
}

extern "C" void kernel_launch(void* const* d_in, const int* in_sizes, int n_in,
                              void* d_out, int out_size, void* d_ws, size_t ws_size,
                              hipStream_t stream) {
    const float* Q   = (const float*)d_in[0];
    const float* Dm  = (const float*)d_in[1];
    const int* dper  = (const int*)d_in[2];
    float* out = (float*)d_out;

    const int DIM  = 1024;
    const int B    = in_sizes[0] / DIM;   // 4096
    const int Ntot = in_sizes[1] / DIM;   // 8192

    unsigned int* Q8 = (unsigned int*)d_ws;
    unsigned int* D8 = Q8 + (size_t)B * DIM / 4;
    float* rowsum = (float*)(D8 + (size_t)Ntot * DIM / 4);
    float* pos = rowsum + B;

    const int qSlots = B * DIM / 16;            // 262144
    const int dSlots = Ntot * DIM / 16;         // 524288
    cvt_kernel<<<(qSlots + dSlots) / 256, 256, 0, stream>>>(
        Q, Dm, Q8, D8, rowsum, qSlots, B, DIM);

    const int nblk = (B / 256) * (Ntot / 256);  // 512 = 8 * 64
    gemm_expsum_kernel<<<nblk, 512, 0, stream>>>(Q8, D8, dper, rowsum, pos, DIM);

    final_kernel<<<1, 1024, 0, stream>>>(rowsum, pos, out, B);
}

// Round 8
// 132.859 us; speedup vs baseline: 3.0750x; 2.5173x over previous
//
#include <hip/hip_runtime.h>

// InfoNCE loss:
//   loss = (1/B) * sum_i [ log(sum_j exp(Q_i . D_j / T)) - Q_i . D_{i*dp} / T ]
//
// R12 = R4/R7's verified 2-barrier loop with a BIGGER TILE that stays inside
// the only register envelope this toolchain has ever run spill-free
// (256-thread blocks; R8-R11 showed 512/1024-thread blocks get a 128/64-reg
// budget and SPILL acc regardless of __launch_bounds__).
//
//  - Tile 256x128 (BM=256, BN=128), BK=128. 4 waves (2M x 2N), per-wave
//    C strip = 128x64 = 32 frags = 128 acc regs. Temps: 4 B-frags (32,
//    read ONCE per K-step) + 4 A-frags (32, two Mh batches) -> peak ~207.
//  - Arithmetic intensity: BM*BN/(BM+BN) = 85 vs 128-tile's 64 (x1.33
//    less staging per FLOP) -- attacks the measured stage-drain cost.
//  - LDS 48KB single buffer -> 3 blocks/CU resident (vs 2.3 at R4),
//    a third MFMA stream to cover each block's serial drain.
//  - Same 2-barrier K-loop, same global_load_lds staging (12 chunks/wave:
//    8 A + 4 B), same epilogue math re-indexed for the new wave grid.
//  - XCD swizzle (R7-verified mechanism): 1024 blocks = 8 XCDs x
//    (8bx x 16by) sub-tiles -> per-XCD slab 2MB A + 2MB B = one 4MB L2.
//
// Tiled global layout (per matrix, unchanged): for 128-row block R, 128-wide
// k-block k0b: 16KB image = 16 chunks x 1KB. Chunk c = rg*2 + kh (rg=0..7
// 16-row group, kh=0..1 64-col half); slot l (16B) holds
//   X[R*128 + rg*16 + (l&15)][k0b*128 + kh*64 + (l>>4)*16 .. +16]   (fp8)
//
// ws layout (~12.1 MB):
//   [0)       Q8  B*K fp8     (4 MB)
//   [B*K)     D8  N*K fp8     (8 MB)
//   [+N*K)    rowsum B f32    (16 KB)  zeroed by cvt kernel
//   [+B*4)    pos    B f32    (16 KB)  written by gemm epilogue

#define TEMP_INV 50.0f
#define PRESCALE 16.0f
#define SCALE_BYTE 123   // e8m0: 2^(123-127) = 2^-4 per operand

typedef int   i32x4 __attribute__((ext_vector_type(4)));
typedef int   i32x8 __attribute__((ext_vector_type(8)));
typedef float f32x4 __attribute__((ext_vector_type(4)));

// ---------------- fp32 -> fp8 e4m3 (x16), pre-tiled; zero rowsum ----------
__global__ void cvt_kernel(const float* __restrict__ Q, const float* __restrict__ Dm,
                           unsigned int* __restrict__ Q8, unsigned int* __restrict__ D8,
                           float* __restrict__ rowsum, int qSlots, int B, int K) {
    const int gid = blockIdx.x * blockDim.x + threadIdx.x;
    if (gid < B) rowsum[gid] = 0.0f;
    const float* src;
    unsigned int* dst;
    int s;
    if (gid < qSlots) { src = Q;  dst = Q8; s = gid; }
    else              { src = Dm; dst = D8; s = gid - qSlots; }
    // Slot permutation within the 64-slot chunk (R7, kept): lane l handles
    // slot ((l&3)<<4)|(l>>2) -> reads coalesce to 256B runs.
    {
        const int l0 = s & 63;
        s = (s & ~63) | (((l0 & 3) << 4) | (l0 >> 2));
    }
    const int l   = s & 63;
    const int c   = (s >> 6) & 15;
    const int k0b = (s >> 10) & 7;
    const int R   = s >> 13;
    const int row = R * 128 + (c >> 1) * 16 + (l & 15);
    const int k   = k0b * 128 + (c & 1) * 64 + (l >> 4) * 16;
    const float* p = src + (size_t)row * K + k;
    unsigned int w[4];
#pragma unroll
    for (int d = 0; d < 4; ++d) {
        float4 v = *(const float4*)(p + d * 4);
        int t = __builtin_amdgcn_cvt_pk_fp8_f32(v.x * PRESCALE, v.y * PRESCALE, 0, false);
        t = __builtin_amdgcn_cvt_pk_fp8_f32(v.z * PRESCALE, v.w * PRESCALE, t, true);
        w[d] = (unsigned int)t;
    }
    *(uint4*)(dst + (size_t)s * 4) = make_uint4(w[0], w[1], w[2], w[3]);
}

// ---------------- fused MX-fp8 GEMM + row sum-exp + pos extraction --------
// grid: 1D 1024 blocks (XCD-swizzled -> bx in [0,16), by in [0,64)),
// 256 threads (4 waves, 2M x 2N), tile 256x128, BK=128, 48KB LDS,
// R4's verified 2-barrier loop.
__global__ __launch_bounds__(256, 2) void gemm_expsum_kernel(
        const unsigned int* __restrict__ Q8, const unsigned int* __restrict__ D8,
        const int* __restrict__ dper,
        float* __restrict__ rowsum, float* __restrict__ pos, int K) {
    __shared__ unsigned int BUF[12288];   // 48KB: A 8192 dw (2 images) + B 4096 dw

    const int tid   = threadIdx.x;
    const int wave  = tid >> 6;
    const int lane  = tid & 63;
    const int wr    = wave >> 1;         // 0..1 -> 128-row half of the 256 rows
    const int wc    = wave & 1;          // 0..1 -> 64-col half of the 128 cols
    const int lquad = lane >> 4;
    const int lm    = lane & 15;
    const int kh    = lquad >> 1;        // 64-col k-half for fragment reads

    // XCD-aware bijective swizzle: 1024 = 8 XCDs x (8bx x 16by) sub-tiles.
    const int f   = blockIdx.x;
    const int xcd = f & 7;
    const int sub = f >> 3;              // 0..127
    const int bx  = (xcd & 1) * 8 + (sub & 7);     // 0..15
    const int by  = (xcd >> 1) * 16 + (sub >> 3);  // 0..63

    const int qbase = bx * 256;
    const int dbase = by * 128;
    const int KB    = K >> 7;            // 8 k-blocks

    // ---- staging bases. A: 8 chunks/wave (ca = wave*8+q, 0..31);
    //      B: 4 chunks/wave (cb = wave*4+q, 0..15). 1KB lane-linear each.
    const unsigned int* QgA = Q8 + (size_t)(2 * bx) * KB * 4096;  // +ca>>4 image
    const unsigned int* DgB = D8 + (size_t)by * KB * 4096;

    // ---- fragment LDS dword offsets ----
    // A frag i (i=0..7): 16-row group ra = wr*8+i of the 256-row tile;
    //   chunk = (ra>>3)*16 + (ra&7)*2 + kh; dword = chunk*256 + slotofs.
    // B frag j (j=0..3): col group gb = wc*4+j; dword = 8192 + (gb*2+kh)*256 + slotofs.
    const int slotofs = ((lquad & 1) * 32 + lm) * 4;   // lo slot; hi adds 64
    const int aofs = (wr * 8 * 2 + kh) * 256 + slotofs;        // i adds (i&7 -> +2*256; i>=8 n/a)
    const int bofs = 8192 + (wc * 8 + kh) * 256 + slotofs;     // j adds 2*256

    f32x4 acc[32];
#pragma unroll
    for (int t = 0; t < 32; ++t) acc[t] = (f32x4){0.f, 0.f, 0.f, 0.f};

#define LDFRAG(dst_, off_) do {                                              \
        i32x4 lo_ = *(const i32x4*)(BUF + (off_));                           \
        i32x4 hi_ = *(const i32x4*)(BUF + (off_) + 64);                      \
        dst_ = __builtin_shufflevector(lo_, hi_, 0, 1, 2, 3, 4, 5, 6, 7);    \
    } while (0)

#define MFMA1(AA, BB, IDX)                                                   \
        acc[IDX] = __builtin_amdgcn_mfma_scale_f32_16x16x128_f8f6f4(         \
            AA, BB, acc[IDX], 0, 0, 0, SCALE_BYTE, 0, SCALE_BYTE)

    for (int kb = 0; kb < KB; ++kb) {
        // ---- stage: 8 A-chunks + 4 B-chunks per wave, lane-linear ----
#pragma unroll
        for (int q = 0; q < 8; ++q) {
            const int ca = wave * 8 + q;                 // 0..31
            const unsigned int* g = QgA + (size_t)(ca >> 4) * KB * 4096
                                    + kb * 4096 + (ca & 15) * 256 + lane * 4;
            __builtin_amdgcn_global_load_lds(
                (const __attribute__((address_space(1))) void*)g,
                (__attribute__((address_space(3))) void*)(BUF + ca * 256 + lane * 4),
                16, 0, 0);
        }
#pragma unroll
        for (int q = 0; q < 4; ++q) {
            const int cb = wave * 4 + q;                 // 0..15
            const unsigned int* g = DgB + kb * 4096 + cb * 256 + lane * 4;
            __builtin_amdgcn_global_load_lds(
                (const __attribute__((address_space(1))) void*)g,
                (__attribute__((address_space(3))) void*)(BUF + 8192 + cb * 256 + lane * 4),
                16, 0, 0);
        }
        __syncthreads();   // drains vmcnt -> LDS tile ready

        // ---- B frags once per K-step ----
        i32x8 B0, B1, B2, B3;
        LDFRAG(B0, bofs + 0 * 512);
        LDFRAG(B1, bofs + 1 * 512);
        LDFRAG(B2, bofs + 2 * 512);
        LDFRAG(B3, bofs + 3 * 512);
        // ---- Mh = 0: A frags 0..3 ----
        {
            i32x8 A0, A1, A2, A3;
            LDFRAG(A0, aofs + 0 * 512);
            LDFRAG(A1, aofs + 1 * 512);
            LDFRAG(A2, aofs + 2 * 512);
            LDFRAG(A3, aofs + 3 * 512);
            MFMA1(A0, B0,  0); MFMA1(A0, B1,  1); MFMA1(A0, B2,  2); MFMA1(A0, B3,  3);
            MFMA1(A1, B0,  4); MFMA1(A1, B1,  5); MFMA1(A1, B2,  6); MFMA1(A1, B3,  7);
            MFMA1(A2, B0,  8); MFMA1(A2, B1,  9); MFMA1(A2, B2, 10); MFMA1(A2, B3, 11);
            MFMA1(A3, B0, 12); MFMA1(A3, B1, 13); MFMA1(A3, B2, 14); MFMA1(A3, B3, 15);
        }
        // ---- Mh = 1: A frags 4..7 ----
        {
            i32x8 A4, A5, A6, A7;
            LDFRAG(A4, aofs + 4 * 512);
            LDFRAG(A5, aofs + 5 * 512);
            LDFRAG(A6, aofs + 6 * 512);
            LDFRAG(A7, aofs + 7 * 512);
            MFMA1(A4, B0, 16); MFMA1(A4, B1, 17); MFMA1(A4, B2, 18); MFMA1(A4, B3, 19);
            MFMA1(A5, B0, 20); MFMA1(A5, B1, 21); MFMA1(A5, B2, 22); MFMA1(A5, B3, 23);
            MFMA1(A6, B0, 24); MFMA1(A6, B1, 25); MFMA1(A6, B2, 26); MFMA1(A6, B3, 27);
            MFMA1(A7, B0, 28); MFMA1(A7, B1, 29); MFMA1(A7, B2, 30); MFMA1(A7, B3, 31);
        }
        __syncthreads();   // all waves done reading before next stage
    }
#undef MFMA1
#undef LDFRAG

    // ---- epilogue. 16x16 C layout: col = lane&15, row = (lane>>4)*4+reg ----
    const int dp = dper[0];
#pragma unroll
    for (int i = 0; i < 8; ++i)
#pragma unroll
        for (int r = 0; r < 4; ++r) {
            const int gr   = qbase + wr * 128 + 16 * i + 4 * lquad + r;
            const int pcol = gr * dp - dbase;   // local col of positive, if here
            float e = 0.0f;
#pragma unroll
            for (int j = 0; j < 4; ++j) {
                float v = acc[i * 4 + j][r];
                if (wc * 64 + 16 * j + lm == pcol) pos[gr] = v * TEMP_INV;
                e += __expf(v * TEMP_INV);
            }
            e += __shfl_xor(e, 1);
            e += __shfl_xor(e, 2);
            e += __shfl_xor(e, 4);
            e += __shfl_xor(e, 8);
            if (lm == 0) atomicAdd(&rowsum[gr], e);
        }
}

// ---------------- final: loss = sum(log(rowsum) - pos)/B ----------------
__global__ void final_kernel(const float* __restrict__ rowsum,
                             const float* __restrict__ pos,
                             float* __restrict__ out, int B) {
    __shared__ float red[16];
    int tid = threadIdx.x;   // 1024 threads
    float s = 0.0f;
    for (int i = tid; i < B; i += blockDim.x)
        s += __logf(rowsum[i]) - pos[i];
    s += __shfl_xor(s, 32);
    s += __shfl_xor(s, 16);
    s += __shfl_xor(s, 8);
    s += __shfl_xor(s, 4);
    s += __shfl_xor(s, 2);
    s += __shfl_xor(s, 1);
    int w = tid >> 6, l = tid & 63;
    if (l == 0) red[w] = s;
    __syncthreads();
    if (tid == 0) {
        float t = 0.0f;
        int nw = blockDim.x >> 6;
        for (int i = 0; i < nw; ++i) t += red[i];
        out[0] = t / (float)B;
    }
}

extern "C" void kernel_launch(void* const* d_in, const int* in_sizes, int n_in,
                              void* d_out, int out_size, void* d_ws, size_t ws_size,
                              hipStream_t stream) {
    const float* Q   = (const float*)d_in[0];
    const float* Dm  = (const float*)d_in[1];
    const int* dper  = (const int*)d_in[2];
    float* out = (float*)d_out;

    const int DIM  = 1024;
    const int B    = in_sizes[0] / DIM;   // 4096
    const int Ntot = in_sizes[1] / DIM;   // 8192

    unsigned int* Q8 = (unsigned int*)d_ws;
    unsigned int* D8 = Q8 + (size_t)B * DIM / 4;
    float* rowsum = (float*)(D8 + (size_t)Ntot * DIM / 4);
    float* pos = rowsum + B;

    const int qSlots = B * DIM / 16;            // 262144
    const int dSlots = Ntot * DIM / 16;         // 524288
    cvt_kernel<<<(qSlots + dSlots) / 256, 256, 0, stream>>>(
        Q, Dm, Q8, D8, rowsum, qSlots, B, DIM);

    const int nblk = (B / 256) * (Ntot / 128);  // 1024 = 8 * 128
    gemm_expsum_kernel<<<nblk, 256, 0, stream>>>(Q8, D8, dper, rowsum, pos, DIM);

    final_kernel<<<1, 1024, 0, stream>>>(rowsum, pos, out, B);
}